// Round 1
// baseline (116.614 us; speedup 1.0000x reference)
//
#include <hip/hip_runtime.h>
#include <math.h>

#define T_TOTAL   131072
#define POSE_FLTS (131072 * 216)      // 28311552
#define POSE_F4   (POSE_FLTS / 4)     // 7077888
#define FLOOR_YC  (-0.93f)
#define GRAV_Y    (-0.0018f)
#define NEG_INF   (-INFINITY)

// ---------------- small math helpers (all constant-indexed after inlining) ---

__device__ __forceinline__ void mat3mul(const float* A, const float* B, float* C) {
#pragma unroll
    for (int r = 0; r < 3; ++r) {
#pragma unroll
        for (int c = 0; c < 3; ++c) {
            C[r * 3 + c] = fmaf(A[r * 3 + 2], B[6 + c],
                           fmaf(A[r * 3 + 1], B[3 + c],
                                A[r * 3 + 0] * B[c]));
        }
    }
}

__device__ __forceinline__ void mva(const float* R, const float* b,
                                    const float* pin, float* pout) {
#pragma unroll
    for (int r = 0; r < 3; ++r) {
        pout[r] = pin[r] + fmaf(R[r * 3 + 2], b[2],
                            fmaf(R[r * 3 + 1], b[1], R[r * 3 + 0] * b[0]));
    }
}

__device__ __forceinline__ void load9(float* M, const float* __restrict__ p) {
#pragma unroll
    for (int k = 0; k < 9; ++k) M[k] = p[k];
}

// select foot component (idx runtime 0..3, c compile-time) without scratch
__device__ __forceinline__ float sel_foot(const float f[12], int idx, int c) {
    float r = f[0 + c];
    r = (idx == 1) ? f[3 + c] : r;
    r = (idx == 2) ? f[6 + c] : r;
    r = (idx == 3) ? f[9 + c] : r;
    return r;
}

// FK for one timestep: needs joints {0,1,2,4,5,7,8} (lower 0..6). Rg7/Rg8 unused.
__device__ __forceinline__ void fk_feet(const float* __restrict__ P,
                                        const float* __restrict__ bone,
                                        float feet[12], float* fmin) {
    float M0[9], M1[9], M2[9], M3[9], M4[9], M5[9], M6[9];
    load9(M0, P + 0);   // joint 0
    load9(M1, P + 9);   // joint 1
    load9(M2, P + 18);  // joint 2
    load9(M3, P + 36);  // joint 4
    load9(M4, P + 45);  // joint 5
    load9(M5, P + 63);  // joint 7
    load9(M6, P + 72);  // joint 8

    float R1[9], R2[9], R3[9], R4[9], R5[9], R6[9];
    mat3mul(M0, M1, R1);
    mat3mul(M0, M2, R2);
    mat3mul(R1, M3, R3);
    mat3mul(R2, M4, R4);
    mat3mul(R3, M5, R5);
    mat3mul(R4, M6, R6);

    float p0[3] = {bone[0], bone[1], bone[2]};
    float p1[3], p2[3], p3[3], p4[3], p5[3], p6[3], p7[3], p8[3];
    mva(M0, bone + 3,  p0, p1);
    mva(M0, bone + 6,  p0, p2);
    mva(R1, bone + 9,  p1, p3);
    mva(R2, bone + 12, p2, p4);
    mva(R3, bone + 15, p3, p5);
    mva(R4, bone + 18, p4, p6);
    mva(R5, bone + 21, p5, p7);
    mva(R6, bone + 24, p6, p8);

    // feet order FEET=[7,5,8,6]
    feet[0] = p7[0]; feet[1]  = p7[1]; feet[2]  = p7[2];
    feet[3] = p5[0]; feet[4]  = p5[1]; feet[5]  = p5[2];
    feet[6] = p8[0]; feet[7]  = p8[1]; feet[8]  = p8[2];
    feet[9] = p6[0]; feet[10] = p6[1]; feet[11] = p6[2];
    *fmin = fminf(fminf(p5[1], p6[1]), fminf(p7[1], p8[1]));
}

// per-thread: compute (vx, a, vz, b) for elements t0 and t0+1
__device__ __forceinline__ void compute2(const float* __restrict__ pose,
                                         const float* __restrict__ bone,
                                         const int* __restrict__ index,
                                         int t0, float v[2][4]) {
    float fB[12], mB;
    fk_feet(pose + (size_t)t0 * 216, bone, fB, &mB);

    if (t0 == 0) {
        v[0][0] = 0.f; v[0][1] = GRAV_Y; v[0][2] = 0.f;
    } else {
        float fA[12], mA;
        fk_feet(pose + (size_t)(t0 - 1) * 216, bone, fA, &mA);
        int idx = index[t0];
        v[0][0] = sel_foot(fA, idx, 0) - sel_foot(fB, idx, 0);
        v[0][1] = GRAV_Y + sel_foot(fA, idx, 1) - sel_foot(fB, idx, 1);
        v[0][2] = sel_foot(fA, idx, 2) - sel_foot(fB, idx, 2);
    }
    v[0][3] = FLOOR_YC - mB;

    float fC[12], mC;
    fk_feet(pose + (size_t)(t0 + 1) * 216, bone, fC, &mC);
    int idx1 = index[t0 + 1];
    v[1][0] = sel_foot(fB, idx1, 0) - sel_foot(fC, idx1, 0);
    v[1][1] = GRAV_Y + sel_foot(fB, idx1, 1) - sel_foot(fC, idx1, 1);
    v[1][2] = sel_foot(fB, idx1, 2) - sel_foot(fC, idx1, 2);
    v[1][3] = FLOOR_YC - mC;
}

// inclusive wave scan (non-commutative compose in lane order: earlier=lower lane)
__device__ __forceinline__ void wave_incl_scan(float& Sx, float& Sz,
                                               float& A, float& B, int lane) {
#pragma unroll
    for (int off = 1; off < 64; off <<= 1) {
        float ox = __shfl_up(Sx, off, 64);
        float oz = __shfl_up(Sz, off, 64);
        float oA = __shfl_up(A, off, 64);
        float oB = __shfl_up(B, off, 64);
        if (lane >= off) {
            Sx += ox;
            Sz += oz;
            B = fmaxf(oB + A, B);  // B uses pre-update A
            A = oA + A;
        }
    }
}

// ---------------- kernels ---------------------------------------------------

__global__ __launch_bounds__(256) void k_copy(const float4* __restrict__ in,
                                              float4* __restrict__ out, int n4) {
    int i = blockIdx.x * blockDim.x + threadIdx.x;
    int stride = gridDim.x * blockDim.x;
    for (; i < n4; i += stride) out[i] = in[i];
}

__global__ __launch_bounds__(256) void k_phase1(const float* __restrict__ pose,
                                                const float* __restrict__ bone,
                                                const int* __restrict__ index,
                                                float4* __restrict__ wsAgg) {
    int tid = threadIdx.x, b = blockIdx.x;
    int t0 = b * 512 + tid * 2;

    float v[2][4];
    compute2(pose, bone, index, t0, v);

    float Sx = v[0][0] + v[1][0];
    float Sz = v[0][2] + v[1][2];
    float A  = v[0][1] + v[1][1];
    float B  = fmaxf(v[0][3] + v[1][1], v[1][3]);

    int lane = tid & 63, wv = tid >> 6;
    wave_incl_scan(Sx, Sz, A, B, lane);

    __shared__ float4 wtot[4];
    if (lane == 63) wtot[wv] = make_float4(Sx, Sz, A, B);
    __syncthreads();
    if (tid == 0) {
        float sx = wtot[0].x, sz = wtot[0].y, aa = wtot[0].z, bb = wtot[0].w;
#pragma unroll
        for (int w = 1; w < 4; ++w) {
            float4 c = wtot[w];
            sx += c.x; sz += c.y;
            bb = fmaxf(bb + c.z, c.w);
            aa += c.z;
        }
        wsAgg[b] = make_float4(sx, sz, aa, bb);
    }
}

__global__ __launch_bounds__(256) void k_phase2(const float4* __restrict__ wsAgg,
                                                float4* __restrict__ wsIn) {
    __shared__ float sx[256], sz[256], sa[256], sb[256];
    int tid = threadIdx.x;
    float4 g = wsAgg[tid];
    sx[tid] = g.x; sz[tid] = g.y; sa[tid] = g.z; sb[tid] = g.w;
    __syncthreads();
    for (int off = 1; off < 256; off <<= 1) {
        float px = 0.f, pz = 0.f, pa = 0.f, pb = NEG_INF;
        bool h = (tid >= off);
        if (h) { px = sx[tid - off]; pz = sz[tid - off]; pa = sa[tid - off]; pb = sb[tid - off]; }
        __syncthreads();
        if (h) {
            float ca = sa[tid], cb = sb[tid];
            sx[tid] = px + sx[tid];
            sz[tid] = pz + sz[tid];
            sb[tid] = fmaxf(pb + ca, cb);
            sa[tid] = pa + ca;
        }
        __syncthreads();
    }
    float ox = 0.f, oz = 0.f, ra = 0.f, rb = NEG_INF;
    if (tid > 0) { ox = sx[tid - 1]; oz = sz[tid - 1]; ra = sa[tid - 1]; rb = sb[tid - 1]; }
    float rin = fmaxf(ra, rb);  // apply composition of prior blocks to r0=0
    wsIn[tid] = make_float4(ox, oz, rin, 0.f);
}

__global__ __launch_bounds__(256) void k_phase3(const float* __restrict__ pose,
                                                const float* __restrict__ bone,
                                                const int* __restrict__ index,
                                                const float4* __restrict__ wsIn,
                                                float* __restrict__ trans) {
    int tid = threadIdx.x, b = blockIdx.x;
    int t0 = b * 512 + tid * 2;

    float v[2][4];
    compute2(pose, bone, index, t0, v);

    float Sx = v[0][0] + v[1][0];
    float Sz = v[0][2] + v[1][2];
    float A  = v[0][1] + v[1][1];
    float B  = fmaxf(v[0][3] + v[1][1], v[1][3]);

    int lane = tid & 63, wv = tid >> 6;
    float ix = Sx, iz = Sz, iA = A, iB = B;
    wave_incl_scan(ix, iz, iA, iB, lane);

    __shared__ float4 wtot[4];
    if (lane == 63) wtot[wv] = make_float4(ix, iz, iA, iB);

    // lane-exclusive from inclusive
    float ex = __shfl_up(ix, 1, 64);
    float ez = __shfl_up(iz, 1, 64);
    float eA = __shfl_up(iA, 1, 64);
    float eB = __shfl_up(iB, 1, 64);
    if (lane == 0) { ex = 0.f; ez = 0.f; eA = 0.f; eB = NEG_INF; }
    __syncthreads();

    // wave prefix (waves before mine, composed in order)
    float wx = 0.f, wz = 0.f, wA = 0.f, wB = NEG_INF;
    for (int w = 0; w < wv; ++w) {
        float4 c = wtot[w];
        wx += c.x; wz += c.y;
        wB = fmaxf(wB + c.z, c.w);
        wA += c.z;
    }

    // thread exclusive-in-block = compose(wavePrefix, laneExclusive)
    float tx = wx + ex, tz = wz + ez;
    float tB = fmaxf(wB + eA, eB);
    float tA = wA + eA;

    float4 bin = wsIn[b];
    float cx = bin.x + tx;
    float cz = bin.y + tz;
    float r  = fmaxf(bin.z + tA, tB);   // root_y entering element t0

    // element t0
    cx += v[0][0];
    r   = fmaxf(r + v[0][1], v[0][3]);
    cz += v[0][2];
    trans[(size_t)t0 * 3 + 0] = cx;
    trans[(size_t)t0 * 3 + 1] = r;
    trans[(size_t)t0 * 3 + 2] = cz;

    // element t0+1
    cx += v[1][0];
    r   = fmaxf(r + v[1][1], v[1][3]);
    cz += v[1][2];
    trans[(size_t)(t0 + 1) * 3 + 0] = cx;
    trans[(size_t)(t0 + 1) * 3 + 1] = r;
    trans[(size_t)(t0 + 1) * 3 + 2] = cz;
}

// ---------------- launch -----------------------------------------------------

extern "C" void kernel_launch(void* const* d_in, const int* in_sizes, int n_in,
                              void* d_out, int out_size, void* d_ws, size_t ws_size,
                              hipStream_t stream) {
    const float* pose  = (const float*)d_in[0];
    const float* bone  = (const float*)d_in[1];
    const int*   index = (const int*)d_in[2];
    float* out   = (float*)d_out;
    float* trans = out + POSE_FLTS;

    float4* wsAgg = (float4*)d_ws;       // 256 entries
    float4* wsIn  = wsAgg + 256;         // 256 entries  (8 KB total)

    k_copy  <<<2048, 256, 0, stream>>>((const float4*)pose, (float4*)out, POSE_F4);
    k_phase1<<<256, 256, 0, stream>>>(pose, bone, index, wsAgg);
    k_phase2<<<1,   256, 0, stream>>>(wsAgg, wsIn);
    k_phase3<<<256, 256, 0, stream>>>(pose, bone, index, wsIn, trans);
}

// Round 2
// 58.438 us; speedup vs baseline: 1.9955x; 1.9955x over previous
//
#include <hip/hip_runtime.h>
#include <math.h>

#define T_TOTAL   131072
#define POSE_FLTS (131072 * 216)      // 28311552
#define POSE_F4   (POSE_FLTS / 4)     // 7077888
#define BT        256                 // timesteps per block
#define NBLK      (T_TOTAL / BT)      // 512
#define FLOOR_YC  (-0.93f)
#define GRAV_Y    (-0.0018f)
#define NEG_INF   (-INFINITY)

// ---------------- small math helpers (constant-indexed after inlining) ------

__device__ __forceinline__ void mat3mul(const float* A, const float* B, float* C) {
#pragma unroll
    for (int r = 0; r < 3; ++r) {
#pragma unroll
        for (int c = 0; c < 3; ++c) {
            C[r * 3 + c] = fmaf(A[r * 3 + 2], B[6 + c],
                           fmaf(A[r * 3 + 1], B[3 + c],
                                A[r * 3 + 0] * B[c]));
        }
    }
}

__device__ __forceinline__ void mva(const float* R, const float* b,
                                    const float* pin, float* pout) {
#pragma unroll
    for (int r = 0; r < 3; ++r) {
        pout[r] = pin[r] + fmaf(R[r * 3 + 2], b[2],
                            fmaf(R[r * 3 + 1], b[1], R[r * 3 + 0] * b[0]));
    }
}

// select foot component from register array (idx runtime, c compile-time)
__device__ __forceinline__ float sel_foot(const float f[12], int idx, int c) {
    float r = f[0 + c];
    r = (idx == 1) ? f[3 + c] : r;
    r = (idx == 2) ? f[6 + c] : r;
    r = (idx == 3) ? f[9 + c] : r;
    return r;
}

// FK for one timestep. Needs joints (lower idx) 0,1,2,4,5,7,8 at float
// offsets 0,9,18,36,45,63,72. Load via aligned float4: [0,28),[36,56),[60,84).
__device__ __forceinline__ void fk_feet(const float* __restrict__ P,
                                        const float* __restrict__ bone,
                                        float feet[12], float* fmin) {
    float Pl[84];
    const float4* p4 = (const float4*)P;   // P is 864B-aligned per timestep
#pragma unroll
    for (int i = 0; i < 7; ++i) {
        float4 q = p4[i];
        Pl[4*i] = q.x; Pl[4*i+1] = q.y; Pl[4*i+2] = q.z; Pl[4*i+3] = q.w;
    }
#pragma unroll
    for (int i = 9; i < 14; ++i) {
        float4 q = p4[i];
        Pl[4*i] = q.x; Pl[4*i+1] = q.y; Pl[4*i+2] = q.z; Pl[4*i+3] = q.w;
    }
#pragma unroll
    for (int i = 15; i < 21; ++i) {
        float4 q = p4[i];
        Pl[4*i] = q.x; Pl[4*i+1] = q.y; Pl[4*i+2] = q.z; Pl[4*i+3] = q.w;
    }

    const float* M0 = Pl + 0;
    const float* M1 = Pl + 9;
    const float* M2 = Pl + 18;
    const float* M3 = Pl + 36;
    const float* M4 = Pl + 45;
    const float* M5 = Pl + 63;
    const float* M6 = Pl + 72;

    float R1[9], R2[9], R3[9], R4[9], R5[9], R6[9];
    mat3mul(M0, M1, R1);
    mat3mul(M0, M2, R2);
    mat3mul(R1, M3, R3);
    mat3mul(R2, M4, R4);
    mat3mul(R3, M5, R5);
    mat3mul(R4, M6, R6);

    float p0[3] = {bone[0], bone[1], bone[2]};
    float p1[3], p2[3], p3[3], p4a[3], p5[3], p6[3], p7[3], p8[3];
    mva(M0, bone + 3,  p0, p1);
    mva(M0, bone + 6,  p0, p2);
    mva(R1, bone + 9,  p1, p3);
    mva(R2, bone + 12, p2, p4a);
    mva(R3, bone + 15, p3, p5);
    mva(R4, bone + 18, p4a, p6);
    mva(R5, bone + 21, p5, p7);
    mva(R6, bone + 24, p6, p8);

    // FEET = [7,5,8,6]
    feet[0] = p7[0]; feet[1]  = p7[1]; feet[2]  = p7[2];
    feet[3] = p5[0]; feet[4]  = p5[1]; feet[5]  = p5[2];
    feet[6] = p8[0]; feet[7]  = p8[1]; feet[8]  = p8[2];
    feet[9] = p6[0]; feet[10] = p6[1]; feet[11] = p6[2];
    *fmin = fminf(fminf(p5[1], p6[1]), fminf(p7[1], p8[1]));
}

// inclusive wave scan (non-commutative compose, earlier = lower lane)
__device__ __forceinline__ void wave_incl_scan(float& Sx, float& Sz,
                                               float& A, float& B, int lane) {
#pragma unroll
    for (int off = 1; off < 64; off <<= 1) {
        float ox = __shfl_up(Sx, off, 64);
        float oz = __shfl_up(Sz, off, 64);
        float oA = __shfl_up(A, off, 64);
        float oB = __shfl_up(B, off, 64);
        if (lane >= off) {
            Sx += ox;
            Sz += oz;
            B = fmaxf(oB + A, B);  // B uses pre-update A
            A = oA + A;
        }
    }
}

// ---------------- kernels ---------------------------------------------------

// Fused: copy block's pose slice + FK once per timestep + per-element scan
// operand to ws + block aggregate.
__global__ __launch_bounds__(256) void k_fused(const float* __restrict__ pose,
                                               const float* __restrict__ bone,
                                               const int* __restrict__ index,
                                               float4* __restrict__ outPose4,
                                               float4* __restrict__ vws,
                                               float4* __restrict__ wsAgg) {
    int b = blockIdx.x, tid = threadIdx.x;
    int t = b * BT + tid;

    // ---- copy this block's 256x216 floats (13824 float4, 54 per thread) ----
    const float4* src = (const float4*)pose + (size_t)b * (BT * 54);
    float4*       dst = outPose4            + (size_t)b * (BT * 54);
#pragma unroll 6
    for (int k = 0; k < 54; ++k) dst[k * 256 + tid] = src[k * 256 + tid];

    // ---- FK for own timestep (reads hit L2/L3 behind the copy stream) -----
    float feet[12], fmin;
    fk_feet(pose + (size_t)t * 216, bone, feet, &fmin);

    __shared__ float fls[BT * 12];
    __shared__ float fprev[12];
#pragma unroll
    for (int k = 0; k < 12; ++k) fls[tid * 12 + k] = feet[k];
    if (tid == 0 && b > 0) {
        float fp[12], mp;
        fk_feet(pose + (size_t)(t - 1) * 216, bone, fp, &mp);
#pragma unroll
        for (int k = 0; k < 12; ++k) fprev[k] = fp[k];
    }
    __syncthreads();

    // ---- velocity ----
    float vx, vy, vz;
    if (t == 0) {
        vx = 0.f; vy = GRAV_Y; vz = 0.f;
    } else {
        int idx = index[t];
        const float* fp = (tid == 0) ? fprev : &fls[(tid - 1) * 12];
        vx = fp[idx * 3 + 0] - sel_foot(feet, idx, 0);
        vy = GRAV_Y + fp[idx * 3 + 1] - sel_foot(feet, idx, 1);
        vz = fp[idx * 3 + 2] - sel_foot(feet, idx, 2);
    }
    float A = vy;
    float B = FLOOR_YC - fmin;
    vws[t] = make_float4(vx, vz, A, B);

    // ---- block aggregate ----
    float Sx = vx, Sz = vz;
    int lane = tid & 63, wv = tid >> 6;
    wave_incl_scan(Sx, Sz, A, B, lane);

    __shared__ float4 wtot[4];
    if (lane == 63) wtot[wv] = make_float4(Sx, Sz, A, B);
    __syncthreads();
    if (tid == 0) {
        float sx = wtot[0].x, sz = wtot[0].y, aa = wtot[0].z, bb = wtot[0].w;
#pragma unroll
        for (int w = 1; w < 4; ++w) {
            float4 c = wtot[w];
            sx += c.x; sz += c.y;
            bb = fmaxf(bb + c.z, c.w);
            aa += c.z;
        }
        wsAgg[b] = make_float4(sx, sz, aa, bb);
    }
}

// Scan of 512 block aggregates -> per-block entering state (x, z, root_y).
__global__ __launch_bounds__(512) void k_phase2(const float4* __restrict__ wsAgg,
                                                float4* __restrict__ wsIn) {
    __shared__ float sx[NBLK], sz[NBLK], sa[NBLK], sb[NBLK];
    int tid = threadIdx.x;
    float4 g = wsAgg[tid];
    sx[tid] = g.x; sz[tid] = g.y; sa[tid] = g.z; sb[tid] = g.w;
    __syncthreads();
    for (int off = 1; off < NBLK; off <<= 1) {
        float px = 0.f, pz = 0.f, pa = 0.f, pb = NEG_INF;
        bool h = (tid >= off);
        if (h) { px = sx[tid - off]; pz = sz[tid - off]; pa = sa[tid - off]; pb = sb[tid - off]; }
        __syncthreads();
        if (h) {
            float ca = sa[tid], cb = sb[tid];
            sx[tid] = px + sx[tid];
            sz[tid] = pz + sz[tid];
            sb[tid] = fmaxf(pb + ca, cb);
            sa[tid] = pa + ca;
        }
        __syncthreads();
    }
    float ox = 0.f, oz = 0.f, ra = 0.f, rb = NEG_INF;
    if (tid > 0) { ox = sx[tid - 1]; oz = sz[tid - 1]; ra = sa[tid - 1]; rb = sb[tid - 1]; }
    float rin = fmaxf(ra, rb);   // root_y entering this block (r0 = 0)
    wsIn[tid] = make_float4(ox, oz, rin, 0.f);
}

// Final: read per-element operand from ws, block scan, add prefix, write trans.
__global__ __launch_bounds__(256) void k_phase3(const float4* __restrict__ vws,
                                                const float4* __restrict__ wsIn,
                                                float* __restrict__ trans) {
    int b = blockIdx.x, tid = threadIdx.x;
    int t = b * BT + tid;

    float4 v = vws[t];
    float vx = v.x, vz = v.y, A0 = v.z, B0 = v.w;

    float ix = vx, iz = vz, iA = A0, iB = B0;
    int lane = tid & 63, wv = tid >> 6;
    wave_incl_scan(ix, iz, iA, iB, lane);

    __shared__ float4 wtot[4];
    if (lane == 63) wtot[wv] = make_float4(ix, iz, iA, iB);
    __syncthreads();

    // prefix over earlier waves (identity = (0,0,0,-inf)), composed in order
    float wx = 0.f, wz = 0.f, wA = 0.f, wB = NEG_INF;
    for (int w = 0; w < wv; ++w) {
        float4 c = wtot[w];
        wx += c.x; wz += c.y;
        wB = fmaxf(wB + c.z, c.w);
        wA += c.z;
    }

    // block-inclusive composition for this thread
    float bx = wx + ix;
    float bz = wz + iz;
    float bB = fmaxf(wB + iA, iB);
    float bA = wA + iA;

    float4 bin = wsIn[b];
    float x = bin.x + bx;
    float z = bin.y + bz;
    float y = fmaxf(bin.z + bA, bB);

    trans[(size_t)t * 3 + 0] = x;
    trans[(size_t)t * 3 + 1] = y;
    trans[(size_t)t * 3 + 2] = z;
}

// ---------------- launch -----------------------------------------------------

extern "C" void kernel_launch(void* const* d_in, const int* in_sizes, int n_in,
                              void* d_out, int out_size, void* d_ws, size_t ws_size,
                              hipStream_t stream) {
    const float* pose  = (const float*)d_in[0];
    const float* bone  = (const float*)d_in[1];
    const int*   index = (const int*)d_in[2];
    float* out   = (float*)d_out;
    float* trans = out + POSE_FLTS;

    float4* vws   = (float4*)d_ws;         // T entries (2 MB)
    float4* wsAgg = vws + T_TOTAL;         // NBLK entries
    float4* wsIn  = wsAgg + NBLK;          // NBLK entries

    k_fused <<<NBLK, 256, 0, stream>>>(pose, bone, index, (float4*)out, vws, wsAgg);
    k_phase2<<<1,    512, 0, stream>>>(wsAgg, wsIn);
    k_phase3<<<NBLK, 256, 0, stream>>>(vws, wsIn, trans);
}